// Round 4
// baseline (794.451 us; speedup 1.0000x reference)
//
#include <hip/hip_runtime.h>

#define NPOS 49
#define NH 8
#define DIMC 384
#define VDC 512
#define SCALE_QK 0.17677669529663687f
#define HS 3584  // per-head scratch in u16: vT[64][56] -> q[49][32]+k[49][32] -> P[49][64]

typedef unsigned short u16;
typedef unsigned int u32;
typedef unsigned char u8;
typedef __attribute__((ext_vector_type(8))) short bf16x8_t;
typedef __attribute__((ext_vector_type(4))) float f32x4_t;
typedef __attribute__((ext_vector_type(2))) u32 u32x2_t;

__device__ __forceinline__ u16 f2bf(float f) {
    unsigned u = __float_as_uint(f);
    u = (u + 0x7fffu + ((u >> 16) & 1u)) >> 16;
    return (u16)u;
}
__device__ __forceinline__ float bf2f(u16 b) {
    return __uint_as_float(((unsigned)b) << 16);
}
__device__ __forceinline__ float fastrcp(float x) {
    return __builtin_amdgcn_rcpf(x);
}
// RNE pack of two f32 -> one u32 of 2 bf16 (lo = a, hi = b)
__device__ __forceinline__ u32 cvt_pk_bf16(float a, float b) {
    u32 r;
    asm("v_cvt_pk_bf16_f32 %0, %1, %2" : "=v"(r) : "v"(a), "v"(b));
    return r;
}
// Load 8 f32 from global and convert to one bf16x8 A-fragment (RNE).
__device__ __forceinline__ bf16x8_t load_x_frag(const float* p) {
    float4 a = *(const float4*)(p);
    float4 b = *(const float4*)(p + 4);
    union { u32 u[4]; bf16x8_t v; } r;
    r.u[0] = cvt_pk_bf16(a.x, a.y);
    r.u[1] = cvt_pk_bf16(a.z, a.w);
    r.u[2] = cvt_pk_bf16(b.x, b.y);
    r.u[3] = cvt_pk_bf16(b.z, b.w);
    return r.v;
}

// Prep: fp32 -> bf16 weight conversion INTO MFMA-FRAGMENT ORDER:
//   frag layout: [och_tile][k_block][l16*32 + quad*8 + e]
__global__ __launch_bounds__(256) void prep_kernel(
    const float* __restrict__ pw, const float* __restrict__ pj,
    u16* __restrict__ wpw, u16* __restrict__ wpj)
{
    int i = blockIdx.x * 256 + threadIdx.x;
    if (i < 1024 * 384) {
        int och = i / 384, k = i - och * 384;
        wpw[((och >> 4) * 12 + (k >> 5)) * 512 + (och & 15) * 32 + (k & 31)] = f2bf(pw[i]);
    }
    if (i < 384 * 512) {
        int o = i / 512, k = i - o * 512;
        wpj[((o >> 4) * 16 + (k >> 5)) * 512 + (o & 15) * 32 + (k & 31)] = f2bf(pj[i]);
    }
}

// One block per batch element. 512 threads = 8 waves, wave = head end-to-end.
// LDS diet for 2 blocks/CU (4 waves/SIMD): x is NOT staged (A-fragments read
// from global f32 + cvt_pk), V never lives block-wide in LDS (per-head scratch
// is time-multiplexed vT -> q/k -> P; post-conv V is register-resident, PV
// B-fragments built via in-wave shfl). Stage 1 runs as two passes (v then q/k)
// to keep live accumulators <= 64 f32.
// LDS (u16), 30660 u16 = 61,320 B:
//   [0,28672)      8 x per-head scratch HS=3584; s_o2 [49][512] swz aliases it
//   [28672,29456)  s_abf bias values f32 [8*49]
//   [29456,30657)  s_bidx bias index u8 [49*49]
__global__ __launch_bounds__(512, 4) void fused_kernel(
    const float* __restrict__ x,
    const float* __restrict__ pwb,
    const float* __restrict__ dww,
    const float* __restrict__ bng, const float* __restrict__ bnb,
    const float* __restrict__ bnm, const float* __restrict__ bnv,
    const float* __restrict__ pjb,
    const u16* __restrict__ wpw, const u16* __restrict__ wpj,
    const float* __restrict__ ab, const int* __restrict__ bidx,
    float* __restrict__ out)
{
    __shared__ u16 lds[30660];
    const int tid  = threadIdx.x;
    const int b    = blockIdx.x;
    const int wv   = tid >> 6;
    const int lane = tid & 63;
    const int quad = lane >> 4;
    const int l16  = lane & 15;

    u16* S    = lds + wv * HS;   // this head's scratch
    u16* Sq   = S;               // q [49][32] (phase 2)
    u16* Sk   = S + 1568;        // k [49][32] (phase 2)
    u16* s_o2 = lds;             // [49][512] XOR-swz (after B3)
    float* s_abf  = (float*)(lds + 28672);
    u8*    s_bidx = (u8*)(lds + 29456);

    // ---- stage 0: compressed bias tables -> LDS (x is NOT staged) ----
    if (tid < 392) s_abf[tid] = ab[tid];
    for (int i = tid; i < 2401; i += 512) s_bidx[i] = (u8)bidx[i];
    __syncthreads();  // B1

    const float* xb = x + (size_t)b * (NPOS * DIMC);

    // ================= stage 1a: pwconv, v-tiles (64 ch) =================
    f32x4_t acc[4][4];
    #pragma unroll
    for (int t = 0; t < 4; ++t)
        #pragma unroll
        for (int mt = 0; mt < 4; ++mt)
            acc[t][mt] = (f32x4_t){0.f, 0.f, 0.f, 0.f};

    #pragma unroll
    for (int ks = 0; ks < 12; ++ks) {
        const int k0 = ks * 32 + quad * 8;
        bf16x8_t afr[4];
        #pragma unroll
        for (int mt = 0; mt < 4; ++mt) {
            int ar = mt * 16 + l16;
            if (ar > 48) ar = 48;
            afr[mt] = load_x_frag(xb + ar * 384 + k0);
        }
        #pragma unroll
        for (int vt = 0; vt < 4; ++vt) {
            bf16x8_t bfr = *(const bf16x8_t*)(
                wpw + ((32 + wv * 4 + vt) * 12 + ks) * 512 + l16 * 32 + quad * 8);
            #pragma unroll
            for (int mt = 0; mt < 4; ++mt)
                acc[vt][mt] = __builtin_amdgcn_mfma_f32_16x16x32_bf16(
                    afr[mt], bfr, acc[vt][mt], 0, 0, 0);
        }
    }
    // vT write: [64 ch][56 pos] in this head's scratch (b64, pos0<49 masked)
    #pragma unroll
    for (int vt = 0; vt < 4; ++vt) {
        const int ch = vt * 16 + l16;
        const float bias = pwb[512 + wv * 64 + ch];
        #pragma unroll
        for (int mt = 0; mt < 4; ++mt) {
            int pos0 = mt * 16 + quad * 4;
            if (pos0 < 49) {
                u32x2_t w;
                w.x = cvt_pk_bf16(acc[vt][mt][0] + bias, acc[vt][mt][1] + bias);
                w.y = cvt_pk_bf16(acc[vt][mt][2] + bias, acc[vt][mt][3] + bias);
                *(u32x2_t*)(S + ch * 56 + pos0) = w;
            }
        }
    }
    asm volatile("s_waitcnt lgkmcnt(0)" ::: "memory");

    // ---- stage 2: depthwise 3x3 + BN + tanh-GELU residual (lane = channel) ----
    float tap[9];
    #pragma unroll
    for (int j = 0; j < 9; ++j) tap[j] = dww[tid * 9 + j];
    const float bsc = bng[tid] * rsqrtf(bnv[tid] + 1e-5f);
    const float bsh = bnb[tid] - bnm[tid] * bsc;

    u32 pr[32];  // packed bf16 V-row (keys 0..63; >=49 zero)
    {
        bf16x8_t tv[7];
        #pragma unroll
        for (int jb = 0; jb < 7; ++jb)
            tv[jb] = *(const bf16x8_t*)(S + lane * 56 + jb * 8);
        float vv[49];
        #pragma unroll
        for (int jb = 0; jb < 7; ++jb)
            #pragma unroll
            for (int e = 0; e < 8; ++e) {
                int p = jb * 8 + e;
                if (p < 49) vv[p] = bf2f((u16)tv[jb][e]);
            }
        float prev = 0.f;
        #pragma unroll
        for (int y = 0; y < 7; ++y)
            #pragma unroll
            for (int xx = 0; xx < 7; ++xx) {
                float s = 0.f;
                #pragma unroll
                for (int ky = 0; ky < 3; ++ky)
                    #pragma unroll
                    for (int kx = 0; kx < 3; ++kx) {
                        int iy = y + ky - 1, ix = xx + kx - 1;
                        if (iy >= 0 && iy < 7 && ix >= 0 && ix < 7)
                            s += tap[ky * 3 + kx] * vv[iy * 7 + ix];
                    }
                s = s * bsc + bsh;
                float p2 = s * s;
                float u2 = s * (1.5957691216057308f + 0.0713548162726f * p2);
                float ee = __expf(u2);
                float g  = s * (1.f - fastrcp(ee + 1.f));
                float rs = vv[y * 7 + xx] + g;
                int p = y * 7 + xx;
                if ((p & 1) == 0) prev = rs;
                else              pr[p >> 1] = cvt_pk_bf16(prev, rs);
            }
        pr[24] = cvt_pk_bf16(prev, 0.f);  // res[48], key 49 = 0
        #pragma unroll
        for (int j = 25; j < 32; ++j) pr[j] = 0;
    }

    // ================= stage 1b: pwconv, q/k tiles (after vT reads) =================
    {
        f32x4_t acc2[4][4];
        #pragma unroll
        for (int t = 0; t < 4; ++t)
            #pragma unroll
            for (int mt = 0; mt < 4; ++mt)
                acc2[t][mt] = (f32x4_t){0.f, 0.f, 0.f, 0.f};
        const int tq0 = wv * 2, tq2 = 16 + wv * 2;
        #pragma unroll
        for (int ks = 0; ks < 12; ++ks) {
            const int k0 = ks * 32 + quad * 8;
            bf16x8_t afr[4];
            #pragma unroll
            for (int mt = 0; mt < 4; ++mt) {
                int ar = mt * 16 + l16;
                if (ar > 48) ar = 48;
                afr[mt] = load_x_frag(xb + ar * 384 + k0);
            }
            #pragma unroll
            for (int it = 0; it < 4; ++it) {
                const int tile = (it < 2) ? (tq0 + it) : (tq2 + it - 2);
                bf16x8_t bfr = *(const bf16x8_t*)(
                    wpw + (tile * 12 + ks) * 512 + l16 * 32 + quad * 8);
                #pragma unroll
                for (int mt = 0; mt < 4; ++mt)
                    acc2[it][mt] = __builtin_amdgcn_mfma_f32_16x16x32_bf16(
                        afr[mt], bfr, acc2[it][mt], 0, 0, 0);
            }
        }
        // D-write q/k into this head's scratch (overwrites vT; vv reads done)
        #pragma unroll
        for (int it = 0; it < 4; ++it) {
            const int tile = (it < 2) ? (tq0 + it) : (tq2 + it - 2);
            const int d = ((it & 1) << 4) + l16;
            const float bias = pwb[tile * 16 + l16];
            u16* base = (it < 2) ? Sq : Sk;
            #pragma unroll
            for (int mt = 0; mt < 4; ++mt)
                #pragma unroll
                for (int r = 0; r < 4; ++r) {
                    int pos = mt * 16 + quad * 4 + r;
                    if (pos < 49) {
                        int dblk = (d >> 3) ^ ((pos >> 2) & 3);
                        base[pos * 32 + (dblk << 3) + (d & 7)] =
                            f2bf(acc2[it][mt][r] + bias);
                    }
                }
        }
    }
    asm volatile("s_waitcnt lgkmcnt(0)" ::: "memory");

    // ---- stage 3: attention (fully wave-local) ----
    {
        bf16x8_t qa[4], kfr[4];
        #pragma unroll
        for (int mt = 0; mt < 4; ++mt) {
            int row = mt * 16 + l16;
            if (row > 48) row = 48;
            int jq = quad ^ ((row >> 2) & 3);
            qa[mt] = *(const bf16x8_t*)(Sq + row * 32 + (jq << 3));
        }
        #pragma unroll
        for (int nt = 0; nt < 4; ++nt) {
            int row = nt * 16 + l16;
            if (row > 48) row = 48;
            int jq = quad ^ ((row >> 2) & 3);
            kfr[nt] = *(const bf16x8_t*)(Sk + row * 32 + (jq << 3));
        }
        // per-mt: QK^T -> no-max softmax -> normalized P-write (P overwrites q/k)
        #pragma unroll
        for (int mt = 0; mt < 4; ++mt) {
            f32x4_t sc[4];
            __builtin_amdgcn_s_setprio(1);
            #pragma unroll
            for (int nt = 0; nt < 4; ++nt) {
                f32x4_t z = (f32x4_t){0.f, 0.f, 0.f, 0.f};
                sc[nt] = __builtin_amdgcn_mfma_f32_16x16x32_bf16(qa[mt], kfr[nt], z, 0, 0, 0);
            }
            __builtin_amdgcn_s_setprio(0);
            #pragma unroll
            for (int r = 0; r < 4; ++r) {
                const int qrow = mt * 16 + quad * 4 + r;
                float e[4];
                #pragma unroll
                for (int nt = 0; nt < 4; ++nt) {
                    const int key = nt * 16 + l16;
                    float val = sc[nt][r] * SCALE_QK;
                    if (key < 49 && qrow < 49)
                        val += s_abf[wv * 49 + s_bidx[qrow * 49 + key]];
                    else
                        val = -1e30f;
                    e[nt] = __expf(val);
                }
                float sum = (e[0] + e[1]) + (e[2] + e[3]);
                #pragma unroll
                for (int off = 1; off < 16; off <<= 1)
                    sum += __shfl_xor(sum, off);
                const float inv = fastrcp(sum);
                if (qrow < 49) {
                    const int sw = qrow & 7;
                    #pragma unroll
                    for (int nt = 0; nt < 4; ++nt) {
                        const int key = nt * 16 + l16;
                        S[qrow * 64 + (((key >> 3) ^ sw) << 3) + (key & 7)] =
                            f2bf(e[nt] * inv);
                    }
                }
            }
        }
        asm volatile("s_waitcnt lgkmcnt(0)" ::: "memory");

        // PV: B-fragments from registers via in-wave shfl (lane c owns channel c)
        bf16x8_t vbf[2][4];
        #pragma unroll
        for (int ksv = 0; ksv < 2; ++ksv)
            #pragma unroll
            for (int nt = 0; nt < 4; ++nt) {
                union { u32 u[4]; bf16x8_t v; } cc;
                const int src = nt * 16 + l16;
                #pragma unroll
                for (int w = 0; w < 4; ++w) {
                    u32 t0 = __shfl(pr[ksv * 16 + 0 + w],  src);
                    u32 t1 = __shfl(pr[ksv * 16 + 4 + w],  src);
                    u32 t2 = __shfl(pr[ksv * 16 + 8 + w],  src);
                    u32 t3 = __shfl(pr[ksv * 16 + 12 + w], src);
                    cc.u[w] = (quad & 2) ? ((quad & 1) ? t3 : t2)
                                         : ((quad & 1) ? t1 : t0);
                }
                vbf[ksv][nt] = cc.v;
            }

        f32x4_t oa[4][4];
        #pragma unroll
        for (int mt = 0; mt < 4; ++mt)
            #pragma unroll
            for (int nt = 0; nt < 4; ++nt)
                oa[mt][nt] = (f32x4_t){0.f, 0.f, 0.f, 0.f};
        #pragma unroll
        for (int ksv = 0; ksv < 2; ++ksv) {
            bf16x8_t pa[4];
            #pragma unroll
            for (int mt = 0; mt < 4; ++mt) {
                int rp = mt * 16 + l16;
                if (rp > 48) rp = 48;
                int slot = (ksv * 4 + quad) ^ (rp & 7);
                pa[mt] = *(const bf16x8_t*)(S + rp * 64 + (slot << 3));
            }
            __builtin_amdgcn_s_setprio(1);
            #pragma unroll
            for (int mt = 0; mt < 4; ++mt)
                #pragma unroll
                for (int nt = 0; nt < 4; ++nt)
                    oa[mt][nt] = __builtin_amdgcn_mfma_f32_16x16x32_bf16(
                        pa[mt], vbf[ksv][nt], oa[mt][nt], 0, 0, 0);
            __builtin_amdgcn_s_setprio(0);
        }
        __syncthreads();  // B3: all P/scratch reads done before o2 overwrites

        #pragma unroll
        for (int mt = 0; mt < 4; ++mt)
            #pragma unroll
            for (int nt = 0; nt < 4; ++nt)
                #pragma unroll
                for (int r = 0; r < 4; ++r) {
                    int pos = mt * 16 + quad * 4 + r;
                    if (pos < 49) {
                        int col = wv * 64 + nt * 16 + l16;
                        int slot = (col >> 3) ^ (pos & 7);
                        s_o2[pos * 512 + (slot << 3) + (col & 7)] =
                            f2bf(oa[mt][nt][r]);
                    }
                }
    }
    __syncthreads();  // B4: o2 visible to all

    // ---- stage 4: proj  out(49x384) = out2(49x512) . proj_w^T ----
    {
        f32x4_t pacc[3][4];
        #pragma unroll
        for (int ntl = 0; ntl < 3; ++ntl)
            #pragma unroll
            for (int mt = 0; mt < 4; ++mt)
                pacc[ntl][mt] = (f32x4_t){0.f, 0.f, 0.f, 0.f};
        #pragma unroll
        for (int ks = 0; ks < 16; ++ks) {
            bf16x8_t afr[4];
            #pragma unroll
            for (int mt = 0; mt < 4; ++mt) {
                int row = mt * 16 + l16;
                if (row > 48) row = 48;
                int slot = (ks * 4 + quad) ^ (row & 7);
                afr[mt] = *(const bf16x8_t*)(s_o2 + row * 512 + (slot << 3));
            }
            #pragma unroll
            for (int ntl = 0; ntl < 3; ++ntl) {
                bf16x8_t wb = *(const bf16x8_t*)(
                    wpj + ((wv * 3 + ntl) * 16 + ks) * 512 + l16 * 32 + quad * 8);
                #pragma unroll
                for (int mt = 0; mt < 4; ++mt)
                    pacc[ntl][mt] = __builtin_amdgcn_mfma_f32_16x16x32_bf16(
                        afr[mt], wb, pacc[ntl][mt], 0, 0, 0);
            }
        }
        float* ob = out + (size_t)b * (NPOS * DIMC);
        #pragma unroll
        for (int ntl = 0; ntl < 3; ++ntl) {
            const int o = (wv * 3 + ntl) * 16 + l16;
            const float pb = pjb[o];
            #pragma unroll
            for (int mt = 0; mt < 4; ++mt)
                #pragma unroll
                for (int r = 0; r < 4; ++r) {
                    int pos = mt * 16 + quad * 4 + r;
                    if (pos < 49) ob[pos * 384 + o] = pacc[ntl][mt][r] + pb;
                }
        }
    }
}

extern "C" void kernel_launch(void* const* d_in, const int* in_sizes, int n_in,
                              void* d_out, int out_size, void* d_ws, size_t ws_size,
                              hipStream_t stream)
{
    const float* x   = (const float*)d_in[0];
    const float* pw  = (const float*)d_in[1];
    const float* pwb = (const float*)d_in[2];
    const float* dww = (const float*)d_in[3];
    const float* bng = (const float*)d_in[4];
    const float* bnb = (const float*)d_in[5];
    const float* bnm = (const float*)d_in[6];
    const float* bnv = (const float*)d_in[7];
    const float* ab  = (const float*)d_in[8];
    const float* pj  = (const float*)d_in[9];
    const float* pjb = (const float*)d_in[10];
    const int*  bidx = (const int*)d_in[11];
    float* out = (float*)d_out;

    // ws layout: pwconv_w bf16 (frag order) | proj_w bf16 (frag order)
    u16* wpw = (u16*)d_ws;
    u16* wpj = wpw + 1024 * 384;

    const int nb = in_sizes[0] / (NPOS * DIMC);

    prep_kernel<<<1536, 256, 0, stream>>>(pw, pj, wpw, wpj);
    fused_kernel<<<nb, 512, 0, stream>>>(x, pwb, dww, bng, bnb, bnm, bnv, pjb,
                                         wpw, wpj, ab, bidx, out);
}

// Round 5
// 645.570 us; speedup vs baseline: 1.2306x; 1.2306x over previous
//
#include <hip/hip_runtime.h>

#define NPOS 49
#define NH 8
#define DIMC 384
#define VDC 512
#define SCALE_QK 0.17677669529663687f

typedef unsigned short u16;
typedef unsigned int u32;
typedef unsigned char u8;
typedef __attribute__((ext_vector_type(8))) short bf16x8_t;
typedef __attribute__((ext_vector_type(4))) float f32x4_t;
typedef __attribute__((ext_vector_type(2))) u32 u32x2_t;

// RNE pack of two f32 -> one u32 of 2 bf16 (lo = a, hi = b); single VALU op.
__device__ __forceinline__ u32 cvt_pk_bf16(float a, float b) {
    u32 r;
    asm("v_cvt_pk_bf16_f32 %0, %1, %2" : "=v"(r) : "v"(a), "v"(b));
    return r;
}
__device__ __forceinline__ u16 f2bf(float f) {
    return (u16)cvt_pk_bf16(f, f);
}
__device__ __forceinline__ float bf2f(u16 b) {
    return __uint_as_float(((unsigned)b) << 16);
}
__device__ __forceinline__ float fastrcp(float x) {
    return __builtin_amdgcn_rcpf(x);
}

// Prep: fp32 -> bf16 weight conversion INTO MFMA-FRAGMENT ORDER:
//   frag layout: [och_tile][k_block][l16*32 + quad*8 + e]
__global__ __launch_bounds__(256) void prep_kernel(
    const float* __restrict__ pw, const float* __restrict__ pj,
    u16* __restrict__ wpw, u16* __restrict__ wpj)
{
    int i = blockIdx.x * 256 + threadIdx.x;
    if (i < 1024 * 384) {
        int och = i / 384, k = i - och * 384;
        wpw[((och >> 4) * 12 + (k >> 5)) * 512 + (och & 15) * 32 + (k & 31)] = f2bf(pw[i]);
    }
    if (i < 384 * 512) {
        int o = i / 512, k = i - o * 512;
        wpj[((o >> 4) * 16 + (k >> 5)) * 512 + (o & 15) * 32 + (k & 31)] = f2bf(pj[i]);
    }
}

// One block per batch element. 512 threads = 8 waves, 1 block/CU (LDS-bound,
// 2 waves/SIMD; round 4 proved 2 blocks/CU forces spills -> stay here).
// Wave w owns head w end-to-end (round-3 structure). NEW: anti-phase passes —
// stage 1 split into V-pass and QK-pass; waves 0-3 run V->conv->QK, waves 4-7
// run QK->V->conv. SIMD s hosts waves {s, s+4} (round-robin), so each SIMD
// always has one wave in VALU-heavy conv while the other runs MFMA passes.
// LDS (u16 units), 79056 u16 = 158,112 B:
//   s_q   [0,12544)      [392][32] bf16, d-block XOR swizzle; P keys 0..31 alias
//   s_k   [12544,25088)  same; P keys 32..63 alias
//   s_v   [25088,57856)  [512][64] XOR-swizzled; s_o2 [pos][520] aliases
//   s_x   [57856,77064)  [49][392] bf16
//   s_abf [77064,77848)  bias values f32 [8*49]
//   s_bidx[77848,...)    bias index  u8  [49*49]
__global__ __launch_bounds__(512, 2) void fused_kernel(
    const float* __restrict__ x,
    const float* __restrict__ pwb,
    const float* __restrict__ dww,
    const float* __restrict__ bng, const float* __restrict__ bnb,
    const float* __restrict__ bnm, const float* __restrict__ bnv,
    const float* __restrict__ pjb,
    const u16* __restrict__ wpw, const u16* __restrict__ wpj,
    const float* __restrict__ ab, const int* __restrict__ bidx,
    float* __restrict__ out)
{
    __shared__ u16 lds[79056];
    const int tid  = threadIdx.x;
    const int b    = blockIdx.x;
    const int wv   = tid >> 6;
    const int lane = tid & 63;
    const int quad = lane >> 4;
    const int l16  = lane & 15;

    u16* s_q  = lds;
    u16* s_k  = lds + 12544;
    u16* s_v  = lds + 25088;
    u16* s_o2 = lds + 25088;
    u16* s_x  = lds + 57856;
    float* s_abf  = (float*)(lds + 77064);
    u8*    s_bidx = (u8*)(lds + 77848);

    // ---- stage 0: x -> LDS bf16 (packed cvt) + compressed bias -> LDS ----
    {
        const float4* xb4 = (const float4*)(x + (size_t)b * (NPOS * DIMC));
        for (int f = tid; f < NPOS * 96; f += 512) {
            float4 v = xb4[f];
            int row = f / 96;
            int cc  = (f - row * 96) * 4;
            u32x2_t w;
            w.x = cvt_pk_bf16(v.x, v.y);
            w.y = cvt_pk_bf16(v.z, v.w);
            *(u32x2_t*)(s_x + row * 392 + cc) = w;
        }
        if (tid < 392) s_abf[tid] = ab[tid];
        for (int i = tid; i < 2401; i += 512) s_bidx[i] = (u8)bidx[i];
    }
    __syncthreads();  // B1: staging visible to all

    // per-channel conv constants (hoisted: latency hides under stage 1)
    float tap[9];
    #pragma unroll
    for (int j = 0; j < 9; ++j) tap[j] = dww[tid * 9 + j];
    const float bsc = bng[tid] * rsqrtf(bnv[tid] + 1e-5f);
    const float bsh = bnb[tid] - bnm[tid] * bsc;

    // ======== stage 1+2: anti-phase two passes, all wave-local ========
    #pragma unroll 1
    for (int phase = 0; phase < 2; ++phase) {
        const int doV = (phase == 0) ^ (wv >= 4 ? 1 : 0);

        int tl[4];
        if (doV) {
            tl[0] = 32 + wv * 4; tl[1] = tl[0] + 1; tl[2] = tl[0] + 2; tl[3] = tl[0] + 3;
        } else {
            tl[0] = wv * 2; tl[1] = wv * 2 + 1; tl[2] = 16 + wv * 2; tl[3] = 17 + wv * 2;
        }

        f32x4_t acc[4][4];
        #pragma unroll
        for (int t = 0; t < 4; ++t)
            #pragma unroll
            for (int mt = 0; mt < 4; ++mt)
                acc[t][mt] = (f32x4_t){0.f, 0.f, 0.f, 0.f};

        #pragma unroll
        for (int ks = 0; ks < 12; ++ks) {
            const int k0 = ks * 32 + quad * 8;
            bf16x8_t afr[4];
            #pragma unroll
            for (int mt = 0; mt < 4; ++mt) {
                int ar = mt * 16 + l16;
                if (ar > 48) ar = 48;  // rows 49..63 discarded; avoid OOB past s_x
                afr[mt] = *(const bf16x8_t*)(s_x + ar * 392 + k0);
            }
            #pragma unroll
            for (int t = 0; t < 4; ++t) {
                bf16x8_t bfr = *(const bf16x8_t*)(
                    wpw + (tl[t] * 12 + ks) * 512 + l16 * 32 + quad * 8);
                #pragma unroll
                for (int mt = 0; mt < 4; ++mt)
                    acc[t][mt] = __builtin_amdgcn_mfma_f32_16x16x32_bf16(
                        afr[mt], bfr, acc[t][mt], 0, 0, 0);
            }
        }

        if (doV) {
            // v D-write: [512][64] swizzled, 4 consecutive pos per b64
            #pragma unroll
            for (int vt = 0; vt < 4; ++vt) {
                const int c  = wv * 64 + vt * 16 + l16;
                const int cb = c & 7;
                const float bias = pwb[512 + c];
                u16* vrow = s_v + c * 64;
                #pragma unroll
                for (int mt = 0; mt < 4; ++mt) {
                    int pos0 = mt * 16 + quad * 4;
                    if (pos0 < 49) {
                        int jb  = pos0 >> 3;
                        int off = pos0 & 7;
                        u32x2_t w;
                        w.x = cvt_pk_bf16(acc[vt][mt][0] + bias, acc[vt][mt][1] + bias);
                        w.y = cvt_pk_bf16(acc[vt][mt][2] + bias, acc[vt][mt][3] + bias);
                        *(u32x2_t*)(vrow + ((jb ^ cb) << 3) + off) = w;
                    }
                }
            }
            asm volatile("s_waitcnt lgkmcnt(0)" ::: "memory");

            // ---- stage 2: depthwise 3x3 + BN + tanh-GELU residual ----
            // c = tid: exactly the v channels this wave just wrote.
            {
                const int c  = tid;
                const int cb = c & 7;
                u16* vrow = s_v + c * 64;
                float vv[56];
                #pragma unroll
                for (int jb = 0; jb < 7; ++jb) {
                    bf16x8_t t = *(const bf16x8_t*)(vrow + ((jb ^ cb) << 3));
                    #pragma unroll
                    for (int e = 0; e < 8; ++e) vv[jb * 8 + e] = bf2f((u16)t[e]);
                }
                float res[64];
                #pragma unroll
                for (int y = 0; y < 7; ++y)
                    #pragma unroll
                    for (int xx = 0; xx < 7; ++xx) {
                        float s = 0.f;
                        #pragma unroll
                        for (int ky = 0; ky < 3; ++ky)
                            #pragma unroll
                            for (int kx = 0; kx < 3; ++kx) {
                                int iy = y + ky - 1, ix = xx + kx - 1;
                                if (iy >= 0 && iy < 7 && ix >= 0 && ix < 7)
                                    s += tap[ky * 3 + kx] * vv[iy * 7 + ix];
                            }
                        s = s * bsc + bsh;
                        float p2 = s * s;
                        float u2 = s * (1.5957691216057308f + 0.0713548162726f * p2);
                        float ee = __expf(u2);
                        float g  = s * (1.f - fastrcp(ee + 1.f));
                        res[y * 7 + xx] = vv[y * 7 + xx] + g;
                    }
                #pragma unroll
                for (int i = 49; i < 64; ++i) res[i] = 0.f;  // NaN shield keys>=49
                #pragma unroll
                for (int jb = 0; jb < 8; ++jb) {
                    u32x2_t w0, w1;
                    w0.x = cvt_pk_bf16(res[jb * 8 + 0], res[jb * 8 + 1]);
                    w0.y = cvt_pk_bf16(res[jb * 8 + 2], res[jb * 8 + 3]);
                    w1.x = cvt_pk_bf16(res[jb * 8 + 4], res[jb * 8 + 5]);
                    w1.y = cvt_pk_bf16(res[jb * 8 + 6], res[jb * 8 + 7]);
                    *(u32x2_t*)(vrow + ((jb ^ cb) << 3))     = w0;
                    *(u32x2_t*)(vrow + ((jb ^ cb) << 3) + 4) = w1;
                }
            }
            asm volatile("s_waitcnt lgkmcnt(0)" ::: "memory");
        } else {
            // q/k D-write (scalar, swizzled; 1-op f2bf)
            #pragma unroll
            for (int it = 0; it < 4; ++it) {
                const int d = ((it & 1) << 4) + l16;
                const float bias = pwb[tl[it] * 16 + l16];
                u16* base = (it < 2) ? s_q : s_k;
                #pragma unroll
                for (int mt = 0; mt < 4; ++mt)
                    #pragma unroll
                    for (int r = 0; r < 4; ++r) {
                        int pos = mt * 16 + quad * 4 + r;
                        if (pos < 49) {
                            int rowi = wv * 49 + pos;
                            int dblk = (d >> 3) ^ ((rowi >> 2) & 3);
                            base[rowi * 32 + (dblk << 3) + (d & 7)] =
                                f2bf(acc[it][mt][r] + bias);
                        }
                    }
            }
            asm volatile("s_waitcnt lgkmcnt(0)" ::: "memory");
        }
    }

    // ---- stage 3: attention, wave = head (fully wave-local) ----
    float invr[4][4];
    {
        const int h = wv;
        bf16x8_t qa[4], kfr[4];
        #pragma unroll
        for (int mt = 0; mt < 4; ++mt) {
            int row = h * 49 + mt * 16 + l16;
            int jq  = quad ^ ((row >> 2) & 3);
            qa[mt] = *(const bf16x8_t*)(s_q + row * 32 + (jq << 3));
        }
        #pragma unroll
        for (int nt = 0; nt < 4; ++nt) {
            int row = h * 49 + nt * 16 + l16;
            int jq  = quad ^ ((row >> 2) & 3);
            kfr[nt] = *(const bf16x8_t*)(s_k + row * 32 + (jq << 3));
        }
        f32x4_t sc[4][4];
        __builtin_amdgcn_s_setprio(1);
        #pragma unroll
        for (int mt = 0; mt < 4; ++mt)
            #pragma unroll
            for (int nt = 0; nt < 4; ++nt) {
                f32x4_t z = (f32x4_t){0.f, 0.f, 0.f, 0.f};
                sc[mt][nt] = __builtin_amdgcn_mfma_f32_16x16x32_bf16(qa[mt], kfr[nt], z, 0, 0, 0);
            }
        __builtin_amdgcn_s_setprio(0);

        // Softmax WITHOUT max-subtraction: logits ~ N(0,1) for this model;
        // f32 exp has ~70 sigma of headroom. Masked keys: exp(-1e30) == 0.
        float pvreg[4][4][4];  // unnormalized exp; [mt][r][nt]
        #pragma unroll
        for (int mt = 0; mt < 4; ++mt)
            #pragma unroll
            for (int r = 0; r < 4; ++r) {
                const int qrow = mt * 16 + quad * 4 + r;
                float e[4];
                #pragma unroll
                for (int nt = 0; nt < 4; ++nt) {
                    const int key = nt * 16 + l16;
                    float val = sc[mt][nt][r] * SCALE_QK;
                    if (key < 49 && qrow < 49)
                        val += s_abf[h * 49 + s_bidx[qrow * 49 + key]];
                    else
                        val = -1e30f;
                    e[nt] = __expf(val);
                }
                float sum = (e[0] + e[1]) + (e[2] + e[3]);
                #pragma unroll
                for (int off = 1; off < 16; off <<= 1)
                    sum += __shfl_xor(sum, off);
                invr[mt][r] = fastrcp(sum);  // applied at o2-write
                pvreg[mt][r][0] = e[0]; pvreg[mt][r][1] = e[1];
                pvreg[mt][r][2] = e[2]; pvreg[mt][r][3] = e[3];
            }

        // P-write into THIS head's own q/k region (keys 0..31 -> q_h, 32..63 -> k_h).
        #pragma unroll
        for (int mt = 0; mt < 4; ++mt)
            #pragma unroll
            for (int r = 0; r < 4; ++r) {
                const int qrow = mt * 16 + quad * 4 + r;
                if (qrow < 49) {
                    const int rowi = h * 49 + qrow;
                    const int sw = (rowi >> 2) & 3;
                    u16* rq = s_q + rowi * 32;
                    u16* rk = s_k + rowi * 32;
                    #pragma unroll
                    for (int nt = 0; nt < 4; ++nt) {
                        const int key = nt * 16 + l16;
                        const int kk  = key & 31;
                        u16* basep = (nt < 2) ? rq : rk;
                        basep[(((kk >> 3) ^ sw) << 3) + (kk & 7)] =
                            f2bf(pvreg[mt][r][nt]);
                    }
                }
            }
        asm volatile("s_waitcnt lgkmcnt(0)" ::: "memory");  // P visible to own reads

        // PV: out_h(49x64) = P(49x64keys) . V(64keys x 64)
        f32x4_t oa[4][4];
        #pragma unroll
        for (int mt = 0; mt < 4; ++mt)
            #pragma unroll
            for (int nt = 0; nt < 4; ++nt)
                oa[mt][nt] = (f32x4_t){0.f, 0.f, 0.f, 0.f};
        #pragma unroll
        for (int ksv = 0; ksv < 2; ++ksv) {
            u16* pbase = ksv ? s_k : s_q;
            bf16x8_t pa[4], vb[4];
            #pragma unroll
            for (int mt = 0; mt < 4; ++mt) {
                int rowi = h * 49 + mt * 16 + l16;
                int jq   = quad ^ ((rowi >> 2) & 3);
                pa[mt] = *(const bf16x8_t*)(pbase + rowi * 32 + (jq << 3));
            }
            #pragma unroll
            for (int nt = 0; nt < 4; ++nt) {
                int rv = h * 64 + nt * 16 + l16;
                vb[nt] = *(const bf16x8_t*)(s_v + rv * 64 + (((ksv * 4 + quad) ^ (rv & 7)) << 3));
            }
            __builtin_amdgcn_s_setprio(1);
            #pragma unroll
            for (int mt = 0; mt < 4; ++mt)
                #pragma unroll
                for (int nt = 0; nt < 4; ++nt)
                    oa[mt][nt] = __builtin_amdgcn_mfma_f32_16x16x32_bf16(
                        pa[mt], vb[nt], oa[mt][nt], 0, 0, 0);
            __builtin_amdgcn_s_setprio(0);
        }
        __syncthreads();  // B3: all waves' v reads done before o2 overwrites region B
        #pragma unroll
        for (int mt = 0; mt < 4; ++mt)
            #pragma unroll
            for (int nt = 0; nt < 4; ++nt)
                #pragma unroll
                for (int r = 0; r < 4; ++r) {
                    int pos = mt * 16 + quad * 4 + r;
                    if (pos < 49)
                        s_o2[pos * 520 + h * 64 + nt * 16 + l16] =
                            f2bf(oa[mt][nt][r] * invr[mt][r]);
                }
    }
    __syncthreads();  // B4: o2 (cross-wave) visible to proj

    // ---- stage 4: proj  out(49x384) = out2(49x512) . proj_w^T ----
    {
        f32x4_t pacc[3][4];
        #pragma unroll
        for (int ntl = 0; ntl < 3; ++ntl)
            #pragma unroll
            for (int mt = 0; mt < 4; ++mt)
                pacc[ntl][mt] = (f32x4_t){0.f, 0.f, 0.f, 0.f};
        #pragma unroll
        for (int ks = 0; ks < 16; ++ks) {
            const int k0 = ks * 32 + quad * 8;
            bf16x8_t afr[4];
            #pragma unroll
            for (int mt = 0; mt < 4; ++mt)
                afr[mt] = *(const bf16x8_t*)(s_o2 + (mt * 16 + l16) * 520 + k0);
            #pragma unroll
            for (int ntl = 0; ntl < 3; ++ntl) {
                bf16x8_t wb = *(const bf16x8_t*)(
                    wpj + ((wv * 3 + ntl) * 16 + ks) * 512 + l16 * 32 + quad * 8);
                #pragma unroll
                for (int mt = 0; mt < 4; ++mt)
                    pacc[ntl][mt] = __builtin_amdgcn_mfma_f32_16x16x32_bf16(
                        afr[mt], wb, pacc[ntl][mt], 0, 0, 0);
            }
        }
        float* ob = out + (size_t)b * (NPOS * DIMC);
        #pragma unroll
        for (int ntl = 0; ntl < 3; ++ntl) {
            const int o = (wv * 3 + ntl) * 16 + l16;
            const float pb = pjb[o];
            #pragma unroll
            for (int mt = 0; mt < 4; ++mt)
                #pragma unroll
                for (int r = 0; r < 4; ++r) {
                    int pos = mt * 16 + quad * 4 + r;
                    if (pos < 49) ob[pos * 384 + o] = pacc[ntl][mt][r] + pb;
                }
        }
    }
}

extern "C" void kernel_launch(void* const* d_in, const int* in_sizes, int n_in,
                              void* d_out, int out_size, void* d_ws, size_t ws_size,
                              hipStream_t stream)
{
    const float* x   = (const float*)d_in[0];
    const float* pw  = (const float*)d_in[1];
    const float* pwb = (const float*)d_in[2];
    const float* dww = (const float*)d_in[3];
    const float* bng = (const float*)d_in[4];
    const float* bnb = (const float*)d_in[5];
    const float* bnm = (const float*)d_in[6];
    const float* bnv = (const float*)d_in[7];
    const float* ab  = (const float*)d_in[8];
    const float* pj  = (const float*)d_in[9];
    const float* pjb = (const float*)d_in[10];
    const int*  bidx = (const int*)d_in[11];
    float* out = (float*)d_out;

    // ws layout: pwconv_w bf16 (frag order) | proj_w bf16 (frag order)
    u16* wpw = (u16*)d_ws;
    u16* wpj = wpw + 1024 * 384;

    const int nb = in_sizes[0] / (NPOS * DIMC);

    prep_kernel<<<1536, 256, 0, stream>>>(pw, pj, wpw, wpj);
    fused_kernel<<<nb, 512, 0, stream>>>(x, pwb, dww, bng, bnb, bnm, bnv, pjb,
                                         wpw, wpj, ab, bidx, out);
}